// Round 1
// baseline (313.949 us; speedup 1.0000x reference)
//
#include <hip/hip_runtime.h>

#define D_DIM 160
#define H_DIM 192
#define W_DIM 160
#define NVOX (D_DIM * H_DIM * W_DIM)
#define NB_STEPS 7

__global__ __launch_bounds__(256) void scale_kernel(const float* __restrict__ in,
                                                    float* __restrict__ out, int n4) {
    int i = blockIdx.x * blockDim.x + threadIdx.x;
    if (i < n4) {
        float4 v = reinterpret_cast<const float4*>(in)[i];
        v.x *= 0.0078125f;
        v.y *= 0.0078125f;
        v.z *= 0.0078125f;
        v.w *= 0.0078125f;
        reinterpret_cast<float4*>(out)[i] = v;
    }
}

__global__ __launch_bounds__(256) void warp_step(const float* __restrict__ v,
                                                 float* __restrict__ out) {
    int idx = blockIdx.x * blockDim.x + threadIdx.x;
    if (idx >= NVOX) return;

    int w = idx % W_DIM;
    int t = idx / W_DIM;
    int h = t % H_DIM;
    int d = t / H_DIM;

    const float* f = v + (size_t)idx * 3;
    float flow_d = f[0];
    float flow_h = f[1];
    float flow_w = f[2];

    // sample location = identity + flow, edge-clamped
    float ld = fminf(fmaxf((float)d + flow_d, 0.0f), (float)(D_DIM - 1));
    float lh = fminf(fmaxf((float)h + flow_h, 0.0f), (float)(H_DIM - 1));
    float lw = fminf(fmaxf((float)w + flow_w, 0.0f), (float)(W_DIM - 1));

    float fd = floorf(ld), fh = floorf(lh), fw = floorf(lw);
    int d0 = (int)fd, h0 = (int)fh, w0 = (int)fw;
    int d1 = min(d0 + 1, D_DIM - 1);
    int h1 = min(h0 + 1, H_DIM - 1);
    int w1 = min(w0 + 1, W_DIM - 1);

    float wd = ld - fd, wh = lh - fh, ww = lw - fw;
    float od = 1.0f - wd, oh = 1.0f - wh, ow = 1.0f - ww;

    // row bases (voxel index of (d, h, 0))
    int r00 = (d0 * H_DIM + h0) * W_DIM;
    int r01 = (d0 * H_DIM + h1) * W_DIM;
    int r10 = (d1 * H_DIM + h0) * W_DIM;
    int r11 = (d1 * H_DIM + h1) * W_DIM;

    float w000 = od * oh * ow;
    float w001 = od * oh * ww;
    float w010 = od * wh * ow;
    float w011 = od * wh * ww;
    float w100 = wd * oh * ow;
    float w101 = wd * oh * ww;
    float w110 = wd * wh * ow;
    float w111 = wd * wh * ww;

    float acc0 = 0.0f, acc1 = 0.0f, acc2 = 0.0f;
#define CORNER(ROW, COL, WT)                               \
    {                                                      \
        const float* p = v + (size_t)((ROW) + (COL)) * 3;  \
        acc0 = fmaf(WT, p[0], acc0);                       \
        acc1 = fmaf(WT, p[1], acc1);                       \
        acc2 = fmaf(WT, p[2], acc2);                       \
    }
    CORNER(r00, w0, w000);
    CORNER(r00, w1, w001);
    CORNER(r01, w0, w010);
    CORNER(r01, w1, w011);
    CORNER(r10, w0, w100);
    CORNER(r10, w1, w101);
    CORNER(r11, w0, w110);
    CORNER(r11, w1, w111);
#undef CORNER

    float* o = out + (size_t)idx * 3;
    o[0] = flow_d + acc0;
    o[1] = flow_h + acc1;
    o[2] = flow_w + acc2;
}

extern "C" void kernel_launch(void* const* d_in, const int* in_sizes, int n_in,
                              void* d_out, int out_size, void* d_ws, size_t ws_size,
                              hipStream_t stream) {
    const float* vec = (const float*)d_in[0];
    float* A = (float*)d_ws;   // ping buffer (59 MB)
    float* B = (float*)d_out;  // pong buffer == output

    int n4 = NVOX * 3 / 4;  // 3,686,400 float4s
    scale_kernel<<<(n4 + 255) / 256, 256, 0, stream>>>(vec, A, n4);

    int grid = (NVOX + 255) / 256;
    for (int s = 0; s < NB_STEPS; ++s) {
        const float* src = (s % 2 == 0) ? A : B;
        float* dst = (s % 2 == 0) ? B : A;
        warp_step<<<grid, 256, 0, stream>>>(src, dst);
    }
    // 7 steps starting at A: A->B->A->B->A->B->A->B, final write lands in d_out.
}

// Round 2
// 302.823 us; speedup vs baseline: 1.0367x; 1.0367x over previous
//
#include <hip/hip_runtime.h>

#define D_DIM 160
#define H_DIM 192
#define W_DIM 160
#define NVOX (D_DIM * H_DIM * W_DIM)
#define NB_STEPS 7

// 12-byte, 4-aligned triple: compiler emits global_load_dwordx3 / store_dwordx3
struct F3 {
    float x, y, z;
};

template <bool SCALED>
__global__ __launch_bounds__(256) void warp_step(const F3* __restrict__ v,
                                                 F3* __restrict__ out) {
    int idx = blockIdx.x * blockDim.x + threadIdx.x;
    if (idx >= NVOX) return;

    int w = idx % W_DIM;
    int t = idx / W_DIM;
    int h = t % H_DIM;
    int d = t / H_DIM;

    F3 f = v[idx];
    const float s = 0.0078125f;  // 1/128
    // effective flow (scaled on the first step)
    float flow_d = SCALED ? f.x * s : f.x;
    float flow_h = SCALED ? f.y * s : f.y;
    float flow_w = SCALED ? f.z * s : f.z;

    float ld = fminf(fmaxf((float)d + flow_d, 0.0f), (float)(D_DIM - 1));
    float lh = fminf(fmaxf((float)h + flow_h, 0.0f), (float)(H_DIM - 1));
    float lw = fminf(fmaxf((float)w + flow_w, 0.0f), (float)(W_DIM - 1));

    float fd = floorf(ld), fh = floorf(lh), fw = floorf(lw);
    int d0 = (int)fd, h0 = (int)fh, w0 = (int)fw;
    int d1 = min(d0 + 1, D_DIM - 1);
    int h1 = min(h0 + 1, H_DIM - 1);
    int w1 = min(w0 + 1, W_DIM - 1);

    float wd = ld - fd, wh = lh - fh, ww = lw - fw;
    float od = 1.0f - wd, oh = 1.0f - wh, ow = 1.0f - ww;

    int r00 = (d0 * H_DIM + h0) * W_DIM;
    int r01 = (d0 * H_DIM + h1) * W_DIM;
    int r10 = (d1 * H_DIM + h0) * W_DIM;
    int r11 = (d1 * H_DIM + h1) * W_DIM;

    float w000 = od * oh * ow;
    float w001 = od * oh * ww;
    float w010 = od * wh * ow;
    float w011 = od * wh * ww;
    float w100 = wd * oh * ow;
    float w101 = wd * oh * ww;
    float w110 = wd * wh * ow;
    float w111 = wd * wh * ww;

    // gather raw values; scale is folded in at the end (out = s*(f + acc))
    float acc0 = 0.0f, acc1 = 0.0f, acc2 = 0.0f;
#define CORNER(ROW, COL, WT)          \
    {                                 \
        F3 c = v[(ROW) + (COL)];      \
        acc0 = fmaf(WT, c.x, acc0);   \
        acc1 = fmaf(WT, c.y, acc1);   \
        acc2 = fmaf(WT, c.z, acc2);   \
    }
    CORNER(r00, w0, w000);
    CORNER(r00, w1, w001);
    CORNER(r01, w0, w010);
    CORNER(r01, w1, w011);
    CORNER(r10, w0, w100);
    CORNER(r10, w1, w101);
    CORNER(r11, w0, w110);
    CORNER(r11, w1, w111);
#undef CORNER

    F3 o;
    if (SCALED) {
        o.x = s * (f.x + acc0);
        o.y = s * (f.y + acc1);
        o.z = s * (f.z + acc2);
    } else {
        o.x = f.x + acc0;
        o.y = f.y + acc1;
        o.z = f.z + acc2;
    }
    out[idx] = o;
}

extern "C" void kernel_launch(void* const* d_in, const int* in_sizes, int n_in,
                              void* d_out, int out_size, void* d_ws, size_t ws_size,
                              hipStream_t stream) {
    const F3* vec = (const F3*)d_in[0];
    F3* A = (F3*)d_ws;   // ping buffer (59 MB)
    F3* B = (F3*)d_out;  // pong buffer == output

    int grid = NVOX / 256;  // 19200, exact

    // Step 1 fuses the 1/128 scale and reads the raw input; writes B (=d_out).
    // Then 6 plain steps alternate B->A->B->A->B->A->B, ending in d_out.
    warp_step<true><<<grid, 256, 0, stream>>>(vec, B);
    for (int s = 1; s < NB_STEPS; ++s) {
        const F3* src = (s % 2 == 1) ? B : A;
        F3* dst = (s % 2 == 1) ? A : B;
        warp_step<false><<<grid, 256, 0, stream>>>(src, dst);
    }
}